// Round 5
// baseline (5602.039 us; speedup 1.0000x reference)
//
#include <hip/hip_runtime.h>

constexpr int B = 2, S = 1024, D = 512, H = 8, F = 3072, TOPK = 64;

typedef unsigned short u16;
typedef unsigned int u32;
typedef __attribute__((ext_vector_type(8))) short bfrag;    // 8 bf16 (4 VGPR)
typedef __attribute__((ext_vector_type(4))) float f32x4;

__device__ __forceinline__ u16 f2bf_rn(float x) {
  u32 u = __float_as_uint(x);
  u32 r = (u + 0x7FFFu + ((u >> 16) & 1u)) >> 16;
  return (u16)r;
}
__device__ __forceinline__ float bf2f(u16 h) {
  return __uint_as_float(((u32)h) << 16);
}

#define GLOAD_LDS16(gp, lp)                                                   \
  __builtin_amdgcn_global_load_lds(                                           \
      (const __attribute__((address_space(1))) u32*)(gp),                     \
      (__attribute__((address_space(3))) u32*)(lp), 16, 0, 0)

// ---- stage one 128x32 bf16 tile (8KB) into LDS, granule-swizzled ----
// LDS slot s (16B granules): row = s>>2, slot sl = s&3 holds global k-granule
// sl ^ ((row>>1)&3). Write side linear (gload_lds); permutation applied on the
// per-lane GLOBAL source address (rule 21: both-sides involution).
__device__ __forceinline__ void stage_tile2(const u16* __restrict__ g, int r0,
                                            int ld, int k0, u16* lds,
                                            int w, int lane) {
#pragma unroll
  for (int p = 0; p < 2; ++p) {
    const int slot = w * 128 + p * 64 + lane;
    const int row = slot >> 2, sl = slot & 3;
    const int gr = sl ^ ((row >> 1) & 3);
    const u16* gp = g + (long)(r0 + row) * ld + k0 + gr * 8;
    u16* lp = lds + (w * 128 + p * 64) * 8;  // wave-uniform base; +lane*16B auto
    GLOAD_LDS16(gp, lp);
  }
}

// read fragment: lane group lg holds global k-granule lg of `row`
__device__ __forceinline__ bfrag frag_at(const u16* tile, int row, int lg) {
  const int idx = row * 32 + ((lg ^ ((row >> 1) & 3)) << 3);
  return *(const bfrag*)(tile + idx);
}

// ============ split-bf16 NT MFMA GEMM v3: 3-stage ring pipeline ============
// C[M,N] (+)= A[M,K] @ Bt[N,K]^T, operands as bf16 hi/lo pairs.
// 3-product AhBh+AhBl+AlBh, f32 MFMA accum. 128x128 block, BK=32,
// 4 waves (2x2 of 64x64). 3-stage LDS ring (96KB), counted vmcnt(8),
// ONE raw s_barrier per K-step (never drains in-flight prefetch).
// Safety proof: barrier at top of iter t => all waves completed iter t-1
// ds_reads (lgkm-waited before their MFMAs); STAGE(t+2) writes buf (t+2)%3
// = (t-1)%3 which no wave touches again until iter t+2's reads, gated by
// vmcnt(8) (in-order VMEM retirement, m135) + the t+2 barrier.
template<bool ACCUM, bool CAUSAL, bool MASK, bool OUTPAIR>
__global__ __launch_bounds__(256) void gemm_split3(
    const u16* __restrict__ Ah0, const u16* __restrict__ Al0,
    const u16* __restrict__ Bh0, const u16* __restrict__ Bl0,
    float* __restrict__ C, u16* __restrict__ Ch, u16* __restrict__ Cl,
    const float* __restrict__ mask0, const float* __restrict__ mask1, int ldm,
    int K, int lda, int ldb, int ldc, int gx, int gy, int NB,
    long sAb, long sAh, long sBb, long sBh, long sCb, long sCh)
{
  __shared__ u16 smem[49152];  // 3 stages x 4 tiles x 4096 u16 = 96 KB

  // bijective XCD swizzle (m204)
  const int nwg = gridDim.x;
  const int q = nwg >> 3, r = nwg & 7;
  const int xcd = blockIdx.x & 7, lid = blockIdx.x >> 3;
  const int sw = (xcd < r ? xcd * (q + 1) : r * (q + 1) + (xcd - r) * q) + lid;
  const int gxy = gx * gy;
  const int z = sw / gxy;
  const int rem = sw - z * gxy;
  const int by = rem / gx;
  const int bx = rem - by * gx;
  const int zb = z % NB, zh = z / NB;

  const u16* Ahp = Ah0 + zb * sAb + zh * sAh;
  const u16* Alp = Al0 + zb * sAb + zh * sAh;
  const u16* Bhp = Bh0 + zb * sBb + zh * sBh;
  const u16* Blp = Bl0 + zb * sBb + zh * sBh;
  const long coff = zb * sCb + zh * sCh;

  const int bm = by * 128, bn = bx * 128;
  const int tid = threadIdx.x;
  const int lane = tid & 63, w = tid >> 6;
  const int wr = w >> 1, wc = w & 1;
  const int lg = lane >> 4, lr = lane & 15;

  f32x4 acc[4][4];
#pragma unroll
  for (int i = 0; i < 4; ++i)
#pragma unroll
    for (int j = 0; j < 4; ++j) {
      acc[i][j][0] = 0.f; acc[i][j][1] = 0.f;
      acc[i][j][2] = 0.f; acc[i][j][3] = 0.f;
    }

  const int kmax = CAUSAL ? min(K, bm + 128) : K;
  const int nt = kmax >> 5;   // >= 4 for every call in this pipeline

#define STAGE(sidx, k0)                                       \
  do {                                                        \
    u16* base_ = smem + (sidx) * 16384;                       \
    stage_tile2(Ahp, bm, lda, (k0), base_,         w, lane);  \
    stage_tile2(Alp, bm, lda, (k0), base_ + 4096,  w, lane);  \
    stage_tile2(Bhp, bn, ldb, (k0), base_ + 8192,  w, lane);  \
    stage_tile2(Blp, bn, ldb, (k0), base_ + 12288, w, lane);  \
  } while (0)

  STAGE(0, 0);
  if (nt > 1) STAGE(1, 32);

  int sidx = 0;  // t % 3 without division
  for (int t = 0; t < nt; ++t) {
    // wait: stage t complete (8 loads of stage t+1 may remain in flight)
    if (t + 1 < nt) {
      asm volatile("s_waitcnt vmcnt(8)" ::: "memory");
    } else {
      asm volatile("s_waitcnt vmcnt(0)" ::: "memory");
    }
    asm volatile("s_barrier" ::: "memory");
    // prefetch stage t+2 into ring slot (t+2)%3 — untouched by any wave now
    const int s2 = (sidx + 2 >= 3) ? sidx - 1 : sidx + 2;
    if (t + 2 < nt) STAGE(s2, (t + 2) << 5);

    const u16* bufp = smem + sidx * 16384;
    bfrag ah[4], al4[4], bh4[4], bl4[4];
#pragma unroll
    for (int i = 0; i < 4; ++i) {
      const int rowA = wr * 64 + i * 16 + lr;
      const int rowB = wc * 64 + i * 16 + lr;
      ah[i]  = frag_at(bufp,          rowA, lg);
      al4[i] = frag_at(bufp + 4096,   rowA, lg);
      bh4[i] = frag_at(bufp + 8192,   rowB, lg);
      bl4[i] = frag_at(bufp + 12288,  rowB, lg);
    }
#pragma unroll
    for (int i = 0; i < 4; ++i)
#pragma unroll
      for (int j = 0; j < 4; ++j) {
        acc[i][j] = __builtin_amdgcn_mfma_f32_16x16x32_bf16(ah[i],  bh4[j], acc[i][j], 0, 0, 0);
        acc[i][j] = __builtin_amdgcn_mfma_f32_16x16x32_bf16(ah[i],  bl4[j], acc[i][j], 0, 0, 0);
        acc[i][j] = __builtin_amdgcn_mfma_f32_16x16x32_bf16(al4[i], bh4[j], acc[i][j], 0, 0, 0);
      }
    sidx = (sidx + 1 >= 3) ? 0 : sidx + 1;
  }
#undef STAGE

  // epilogue: C/D layout col = lane&15, row = (lane>>4)*4 + reg
  const float* mp_ = MASK ? (zh ? mask1 : mask0) : nullptr;
#pragma unroll
  for (int i = 0; i < 4; ++i)
#pragma unroll
    for (int j = 0; j < 4; ++j)
#pragma unroll
      for (int rr = 0; rr < 4; ++rr) {
        const int row = bm + wr * 64 + i * 16 + lg * 4 + rr;
        const int col = bn + wc * 64 + j * 16 + lr;
        float v = acc[i][j][rr];
        if (MASK) v *= mp_[(long)row * ldm + col];
        const long ci = coff + (long)row * ldc + col;
        if (OUTPAIR) {
          const u16 h = f2bf_rn(v);
          Ch[ci] = h;
          Cl[ci] = f2bf_rn(v - bf2f(h));
        } else if (ACCUM) {
          C[ci] += v;
        } else {
          C[ci] = v;
        }
      }
}

// ================= small kernels =================
__global__ void split_pair(const float* __restrict__ in, u16* __restrict__ oh,
                           u16* __restrict__ ol, long n) {
  for (long i = blockIdx.x * (long)blockDim.x + threadIdx.x; i < n;
       i += gridDim.x * (long)blockDim.x) {
    const float x = in[i];
    const u16 h = f2bf_rn(x);
    oh[i] = h;
    ol[i] = f2bf_rn(x - bf2f(h));
  }
}

// probs[:, h] (both b) split into a contiguous [b][S][S] pair
__global__ void split_pair_probs(const float* __restrict__ probs, int h,
                                 u16* __restrict__ oh, u16* __restrict__ ol) {
  const long n = (long)B << 20;  // B * S * S, S*S = 2^20
  for (long i = blockIdx.x * (long)blockDim.x + threadIdx.x; i < n;
       i += gridDim.x * (long)blockDim.x) {
    const long b = i >> 20;
    const long rr = i & ((1L << 20) - 1);
    const float x = probs[(b * H + h) * (1L << 20) + rr];
    const u16 hh = f2bf_rn(x);
    oh[i] = hh;
    ol[i] = f2bf_rn(x - bf2f(hh));
  }
}

// out pair [C][R] = transpose of in [R][C], optional per-input-row divisor
__global__ __launch_bounds__(256) void transpose_split(
    const float* __restrict__ in, const float* __restrict__ divv,
    u16* __restrict__ oh, u16* __restrict__ ol, int R, int C) {
  __shared__ float t[32][33];
  const int bx = blockIdx.x * 32;  // C dim
  const int by = blockIdx.y * 32;  // R dim
  const int x = threadIdx.x & 31, y = threadIdx.x >> 5;
#pragma unroll
  for (int j = 0; j < 4; ++j) {
    const int rr = by + y + j * 8;
    float v = in[(long)rr * C + bx + x];
    if (divv) v /= divv[rr];
    t[y + j * 8][x] = v;
  }
  __syncthreads();
#pragma unroll
  for (int j = 0; j < 4; ++j) {
    const int c = bx + y + j * 8;
    const float v = t[x][y + j * 8];
    const u16 h = f2bf_rn(v);
    oh[(long)c * R + by + x] = h;
    ol[(long)c * R + by + x] = f2bf_rn(v - bf2f(h));
  }
}

__global__ void cvec_partial(const float* __restrict__ W_OV,
                             const float* __restrict__ ub1,
                             const float* __restrict__ ub2,
                             float* __restrict__ ctmp) {
  const int o = blockIdx.x * 256 + threadIdx.x;
  const int h = blockIdx.y;
  const float* W = W_OV + (long)h * D * D;
  float acc = 0.f;
  for (int i = 0; i < D; ++i)
    acc = fmaf(W[(long)i * D + o], ub1[i] + ub2[i], acc);
  ctmp[h * D + o] = acc;
}

__global__ void cvec_reduce(const float* __restrict__ ctmp, float* __restrict__ cvec) {
  const int o = blockIdx.x * blockDim.x + threadIdx.x;
  if (o < D) {
    float a = 0.f;
    for (int h = 0; h < H; ++h) a += ctmp[h * D + o];
    cvec[o] = a;
  }
}

__global__ __launch_bounds__(64) void bias_vec(
    const float* __restrict__ enc_w, const float* __restrict__ b_O,
    const float* __restrict__ b_dec, const float* __restrict__ enc_b,
    const float* __restrict__ cvec, float* __restrict__ bias0,
    float* __restrict__ evec) {
  const int f = blockIdx.x;
  const int l = threadIdx.x;
  float s1 = 0.f, s2 = 0.f;
  for (int o = l; o < D; o += 64) {
    const float w = enc_w[(long)f * D + o];
    s1 = fmaf(w, b_O[o] - b_dec[o], s1);
    s2 = fmaf(w, cvec[o], s2);
  }
  for (int off = 32; off > 0; off >>= 1) {
    s1 += __shfl_down(s1, off);
    s2 += __shfl_down(s2, off);
  }
  if (l == 0) { bias0[f] = s1 + enc_b[f]; evec[f] = s2; }
}

__global__ __launch_bounds__(256) void transpose_dw(const float* __restrict__ in,
                                                    float* __restrict__ out) {
  __shared__ float t[32][33];
  const int bx = blockIdx.x * 32;
  const int by = blockIdx.y * 32;
  const int x = threadIdx.x & 31, y = threadIdx.x >> 5;
#pragma unroll
  for (int j = 0; j < 4; ++j) {
    const int row = y + j * 8;
    t[row][x] = in[(long)(by + row) * F + bx + x];
  }
  __syncthreads();
#pragma unroll
  for (int j = 0; j < 4; ++j) {
    const int row = y + j * 8;
    out[(long)(bx + row) * D + by + x] = t[x][row];
  }
}

// top-64 of (bias0 + evec/ln + P) per row; relu; scatter; record.
__global__ __launch_bounds__(256) void topk_fused(
    const float* __restrict__ P, const float* __restrict__ bias0,
    const float* __restrict__ evec, const float* __restrict__ ln,
    float* __restrict__ feat, float* __restrict__ topv, int* __restrict__ topi) {
  const int row = blockIdx.x;  // b*S+s
  const float rln = 1.f / ln[row];
  const float* p0 = P + (long)row * F;
  __shared__ float vals[F];
  __shared__ float rv[256];
  __shared__ int ri[256];
  for (int j = threadIdx.x; j < F; j += 256)
    vals[j] = bias0[j] + evec[j] * rln + p0[j];
  __syncthreads();
  for (int it = 0; it < TOPK; ++it) {
    float best = -3.4e38f;
    int bi = F;
    for (int j = threadIdx.x; j < F; j += 256) {
      const float v = vals[j];
      if (v > best) { best = v; bi = j; }  // strict > keeps lowest index
    }
    rv[threadIdx.x] = best; ri[threadIdx.x] = bi;
    __syncthreads();
    for (int s2 = 128; s2 > 0; s2 >>= 1) {
      if (threadIdx.x < s2) {
        const float ov = rv[threadIdx.x + s2];
        const int oi = ri[threadIdx.x + s2];
        if (ov > rv[threadIdx.x] ||
            (ov == rv[threadIdx.x] && oi < ri[threadIdx.x])) {
          rv[threadIdx.x] = ov; ri[threadIdx.x] = oi;
        }
      }
      __syncthreads();
    }
    if (threadIdx.x == 0) {
      const int idx = ri[0];
      const float v = fmaxf(rv[0], 0.f);
      feat[(long)row * F + idx] = v;
      topv[row * TOPK + it] = v;
      topi[row * TOPK + it] = idx;
      vals[idx] = -3.4e38f;
    }
    __syncthreads();
  }
}

__global__ __launch_bounds__(256) void recon_kernel(
    const float* __restrict__ topv, const int* __restrict__ topi,
    const float* __restrict__ dec_wT, const float* __restrict__ b_dec,
    float* __restrict__ recon) {
  const int row = blockIdx.x;
  __shared__ float sv[TOPK];
  __shared__ int si[TOPK];
  if (threadIdx.x < TOPK) {
    sv[threadIdx.x] = topv[row * TOPK + threadIdx.x];
    si[threadIdx.x] = topi[row * TOPK + threadIdx.x];
  }
  __syncthreads();
  const int d0 = threadIdx.x, d1 = threadIdx.x + 256;
  float a0 = b_dec[d0], a1 = b_dec[d1];
  for (int j = 0; j < TOPK; ++j) {
    const float v = sv[j];
    const float* wp = dec_wT + (long)si[j] * D;
    a0 = fmaf(v, wp[d0], a0);
    a1 = fmaf(v, wp[d1], a1);
  }
  recon[(long)row * D + d0] = a0;
  recon[(long)row * D + d1] = a1;
}

// ================= launch =================
extern "C" void kernel_launch(void* const* d_in, const int* in_sizes, int n_in,
                              void* d_out, int out_size, void* d_ws, size_t ws_size,
                              hipStream_t stream) {
  const float* resid = (const float*)d_in[0];
  const float* ln    = (const float*)d_in[1];
  const float* probs = (const float*)d_in[2];
  const float* W_OV  = (const float*)d_in[3];
  const float* b_O   = (const float*)d_in[4];
  const float* enc_w = (const float*)d_in[5];
  const float* enc_b = (const float*)d_in[6];
  const float* b_dec = (const float*)d_in[7];
  const float* dec_w = (const float*)d_in[8];
  const float* up_dec_[2]  = {(const float*)d_in[9], (const float*)d_in[13]};
  const float* up_bdec_[2] = {(const float*)d_in[10], (const float*)d_in[14]};
  const float* pf_[2]      = {(const float*)d_in[11], (const float*)d_in[15]};
  const float* mask_[2]    = {(const float*)d_in[12], (const float*)d_in[16]};

  float* out_feat  = (float*)d_out;
  float* out_recon = out_feat + (size_t)B * S * F;

  // ---- workspace layout (~161 MB, proven-safe budget) ----
  float* ws = (float*)d_ws;
  size_t o = 0;
  float* P     = ws + o; o += (size_t)B * S * F;          // 25.2 MB
  float* bias0 = ws + o; o += F;
  float* evec  = ws + o; o += F;
  float* cvec  = ws + o; o += D;
  float* ctmp  = ws + o; o += (size_t)H * D;
  float* topv  = ws + o; o += (size_t)B * S * TOPK;
  int*   topi  = (int*)(ws + o); o += (size_t)B * S * TOPK;
  u16* encwPh = (u16*)(ws + o); o += (size_t)F * D / 2;
  u16* encwPl = (u16*)(ws + o); o += (size_t)F * D / 2;
  u16* wovPh  = (u16*)(ws + o); o += (size_t)H * D * D / 2;
  u16* wovPl  = (u16*)(ws + o); o += (size_t)H * D * D / 2;
  u16* udTh   = (u16*)(ws + o); o += (size_t)2 * F * D / 2;   // [u][F][D]
  u16* udTl   = (u16*)(ws + o); o += (size_t)2 * F * D / 2;
  u16* actTh  = (u16*)(ws + o); o += (size_t)B * D * S / 2;   // [b][D][S]
  u16* actTl  = (u16*)(ws + o); o += (size_t)B * D * S / 2;
  u16* Gh     = (u16*)(ws + o); o += (size_t)2 * B * F * S / 2;  // [u][b][F][S]
  u16* Gl     = (u16*)(ws + o); o += (size_t)2 * B * F * S / 2;
  u16* Phh    = (u16*)(ws + o); o += (size_t)B * S * S / 2;   // per-h probs pair
  u16* Phl    = (u16*)(ws + o); o += (size_t)B * S * S / 2;
  u16* Ehh    = (u16*)(ws + o); o += (size_t)F * 512 / 2;     // per-h Eh pair
  u16* Ehl    = (u16*)(ws + o); o += (size_t)F * 512 / 2;
  const size_t xoff = o;                                      // dec_wT alias
  u16* Xh     = (u16*)(ws + o); o += (size_t)B * S * 3072 / 2;  // per-h X pair
  u16* Xl     = (u16*)(ws + o); o += (size_t)B * S * 3072 / 2;
  u16* vwh    = (u16*)(ws + o); o += (size_t)F * 3072 / 2;    // per-(h,u) vw pair
  u16* vwl    = (u16*)(ws + o); o += (size_t)F * 3072 / 2;
  float* dec_wT = ws + xoff;  // used only after h-loop (X region dead by then)

  hipMemsetAsync(out_feat, 0, sizeof(float) * (size_t)B * S * F, stream);
  hipMemsetAsync(P, 0, sizeof(float) * (size_t)B * S * F, stream);

  // ---- operand prep ----
  split_pair<<<1024, 256, 0, stream>>>(enc_w, encwPh, encwPl, (long)F * D);
  split_pair<<<1024, 256, 0, stream>>>(W_OV, wovPh, wovPl, (long)H * D * D);
  for (int b = 0; b < B; ++b)
    transpose_split<<<dim3(D / 32, S / 32), 256, 0, stream>>>(
        resid + (size_t)b * S * D, ln + (size_t)b * S,
        actTh + (size_t)b * D * S, actTl + (size_t)b * D * S, S, D);
  for (int u = 0; u < 2; ++u) {
    for (int b = 0; b < B; ++b)
      transpose_split<<<dim3(F / 32, S / 32), 256, 0, stream>>>(
          pf_[u] + (size_t)b * S * F, ln + (size_t)b * S,
          Gh + ((size_t)u * B + b) * F * S, Gl + ((size_t)u * B + b) * F * S,
          S, F);
    transpose_split<<<dim3(F / 32, D / 32), 256, 0, stream>>>(
        up_dec_[u], nullptr, udTh + (size_t)u * F * D, udTl + (size_t)u * F * D,
        D, F);
  }
  cvec_partial<<<dim3(2, 8), 256, 0, stream>>>(W_OV, up_bdec_[0], up_bdec_[1], ctmp);
  cvec_reduce<<<2, 256, 0, stream>>>(ctmp, cvec);
  bias_vec<<<F, 64, 0, stream>>>(enc_w, b_O, b_dec, enc_b, cvec, bias0, evec);

  // ---- per-head pipeline ----
  for (int h = 0; h < H; ++h) {
    // probs[:,h] split pair (both b, one dispatch)
    split_pair_probs<<<2048, 256, 0, stream>>>(probs, h, Phh, Phl);
    // Eh[f,i] = sum_o enc_w[f,o] * W_OV[h,i,o] -> pair [F][512]
    gemm_split3<false, false, false, true><<<96, 256, 0, stream>>>(
        encwPh, encwPl, wovPh + (size_t)h * D * D, wovPl + (size_t)h * D * D,
        nullptr, Ehh, Ehl, nullptr, nullptr, 0,
        512, 512, 512, 512, 4, 24, 1, 0L, 0L, 0L, 0L, 0L, 0L);
    // Xact[b][q][d] = probs_h[b] @ actT[b]^T (causal) -> pair, ldc=512
    gemm_split3<false, true, false, true><<<64, 256, 0, stream>>>(
        Phh, Phl, actTh, actTl, nullptr, Xh, Xl, nullptr, nullptr, 0,
        S, S, S, 512, 4, 8, 2,
        (long)S * S, 0L, (long)D * S, 0L, (long)S * 512, 0L);
    // P[b] += Xact[b] @ Eh^T  (K=512)
    gemm_split3<true, false, false, false><<<384, 256, 0, stream>>>(
        Xh, Xl, Ehh, Ehl, P, nullptr, nullptr, nullptr, nullptr, 0,
        512, 512, 512, F, 24, 8, 2,
        (long)S * 512, 0L, 0L, 0L, (long)S * F, 0L);

    for (int u = 0; u < 2; ++u) {
      // X[b][q][n] = probs_h[b] @ G_u[b]^T (causal) -> pair, ldc=3072
      gemm_split3<false, true, false, true><<<384, 256, 0, stream>>>(
          Phh, Phl, Gh + (size_t)u * B * F * S, Gl + (size_t)u * B * F * S,
          nullptr, Xh, Xl, nullptr, nullptr, 0,
          S, S, S, 3072, 24, 8, 2,
          (long)S * S, 0L, (long)F * S, 0L, (long)S * 3072, 0L);
      // vw[d][n] = (Eh @ udT_u^T)[d][n] * mask_u[d][n] -> pair [F][3072]
      gemm_split3<false, false, true, true><<<576, 256, 0, stream>>>(
          Ehh, Ehl, udTh + (size_t)u * F * D, udTl + (size_t)u * F * D,
          nullptr, vwh, vwl, mask_[u], nullptr, F,
          512, 512, 512, 3072, 24, 24, 1, 0L, 0L, 0L, 0L, 0L, 0L);
      // P[b] += X[b] @ vw^T  (K=3072)
      gemm_split3<true, false, false, false><<<384, 256, 0, stream>>>(
          Xh, Xl, vwh, vwl, P, nullptr, nullptr, nullptr, nullptr, 0,
          3072, 3072, 3072, F, 24, 8, 2,
          (long)S * 3072, 0L, 0L, 0L, (long)S * F, 0L);
    }
  }

  // ---- tail: dec_w transpose (into dead X region), topk, recon ----
  transpose_dw<<<dim3(F / 32, D / 32), 256, 0, stream>>>(dec_w, dec_wT);
  topk_fused<<<B * S, 256, 0, stream>>>(P, bias0, evec, ln, out_feat, topv, topi);
  recon_kernel<<<B * S, 256, 0, stream>>>(topv, topi, dec_wT, b_dec, out_recon);
}

// Round 7
// 4425.584 us; speedup vs baseline: 1.2658x; 1.2658x over previous
//
#include <hip/hip_runtime.h>

constexpr int B = 2, S = 1024, D = 512, H = 8, F = 3072, TOPK = 64;

typedef unsigned short u16;
typedef unsigned int u32;
typedef __attribute__((ext_vector_type(8))) short bfrag;    // 8 bf16 (4 VGPR)
typedef __attribute__((ext_vector_type(4))) float f32x4;

__device__ __forceinline__ u16 f2bf_rn(float x) {
  u32 u = __float_as_uint(x);
  u32 r = (u + 0x7FFFu + ((u >> 16) & 1u)) >> 16;
  return (u16)r;
}
__device__ __forceinline__ float bf2f(u16 h) {
  return __uint_as_float(((u32)h) << 16);
}

#define GLOAD_LDS16(gp, lp)                                                   \
  __builtin_amdgcn_global_load_lds(                                           \
      (const __attribute__((address_space(1))) u32*)(gp),                     \
      (__attribute__((address_space(3))) u32*)(lp), 16, 0, 0)

// ---- stage one 128x32 bf16 tile (8KB) into LDS, granule-swizzled ----
// LDS slot s (16B granules): row = s>>2, slot sl = s&3 holds global k-granule
// sl ^ ((row>>1)&3). Write side linear (gload_lds); permutation applied on the
// per-lane GLOBAL source address (rule 21: both-sides involution).
__device__ __forceinline__ void stage_tile2(const u16* __restrict__ g, int r0,
                                            int ld, int k0, u16* lds,
                                            int w, int lane) {
#pragma unroll
  for (int p = 0; p < 2; ++p) {
    const int slot = w * 128 + p * 64 + lane;
    const int row = slot >> 2, sl = slot & 3;
    const int gr = sl ^ ((row >> 1) & 3);
    const u16* gp = g + (long)(r0 + row) * ld + k0 + gr * 8;
    u16* lp = lds + (w * 128 + p * 64) * 8;  // wave-uniform base; +lane*16B auto
    GLOAD_LDS16(gp, lp);
  }
}

// read fragment: lane group lg holds global k-granule lg of `row`
__device__ __forceinline__ bfrag frag_at(const u16* tile, int row, int lg) {
  const int idx = row * 32 + ((lg ^ ((row >> 1) & 3)) << 3);
  return *(const bfrag*)(tile + idx);
}

// ============ split-bf16 NT MFMA GEMM (round-4 proven, verbatim) ============
// C[M,N] (+)= A[M,K] @ Bt[N,K]^T, operands as bf16 hi/lo pairs.
// 3-product AhBh+AhBl+AlBh, f32 MFMA accum. 128x128 block, BK=32,
// 4 waves (2x2 of 64x64). Double-buffered LDS (64KB), T3 2-phase.
// 1D grid with bijective XCD swizzle; z -> (zb = z%NB, zh = z/NB) offsets.
template<bool ACCUM, bool CAUSAL, bool MASK, bool OUTPAIR>
__global__ __launch_bounds__(256) void gemm_split3(
    const u16* __restrict__ Ah0, const u16* __restrict__ Al0,
    const u16* __restrict__ Bh0, const u16* __restrict__ Bl0,
    float* __restrict__ C, u16* __restrict__ Ch, u16* __restrict__ Cl,
    const float* __restrict__ mask0, const float* __restrict__ mask1, int ldm,
    int K, int lda, int ldb, int ldc, int gx, int gy, int NB,
    long sAb, long sAh, long sBb, long sBh, long sCb, long sCh)
{
  __shared__ u16 smem[32768];  // 2 bufs x 4 tiles x 4096 u16 = 64 KB

  // bijective XCD swizzle (m204)
  const int nwg = gridDim.x;
  const int q = nwg >> 3, r = nwg & 7;
  const int xcd = blockIdx.x & 7, lid = blockIdx.x >> 3;
  const int sw = (xcd < r ? xcd * (q + 1) : r * (q + 1) + (xcd - r) * q) + lid;
  const int gxy = gx * gy;
  const int z = sw / gxy;
  const int rem = sw - z * gxy;
  const int by = rem / gx;
  const int bx = rem - by * gx;
  const int zb = z % NB, zh = z / NB;

  const u16* Ahp = Ah0 + zb * sAb + zh * sAh;
  const u16* Alp = Al0 + zb * sAb + zh * sAh;
  const u16* Bhp = Bh0 + zb * sBb + zh * sBh;
  const u16* Blp = Bl0 + zb * sBb + zh * sBh;
  const long coff = zb * sCb + zh * sCh;

  const int bm = by * 128, bn = bx * 128;
  const int tid = threadIdx.x;
  const int lane = tid & 63, w = tid >> 6;
  const int wr = w >> 1, wc = w & 1;
  const int lg = lane >> 4, lr = lane & 15;

  f32x4 acc[4][4];
#pragma unroll
  for (int i = 0; i < 4; ++i)
#pragma unroll
    for (int j = 0; j < 4; ++j) {
      acc[i][j][0] = 0.f; acc[i][j][1] = 0.f;
      acc[i][j][2] = 0.f; acc[i][j][3] = 0.f;
    }

  const int kmax = CAUSAL ? min(K, bm + 128) : K;
  const int nt = kmax >> 5;

#define STAGE(buf, k0)                                        \
  do {                                                        \
    u16* base_ = smem + (buf) * 16384;                        \
    stage_tile2(Ahp, bm, lda, (k0), base_,         w, lane);  \
    stage_tile2(Alp, bm, lda, (k0), base_ + 4096,  w, lane);  \
    stage_tile2(Bhp, bn, ldb, (k0), base_ + 8192,  w, lane);  \
    stage_tile2(Blp, bn, ldb, (k0), base_ + 12288, w, lane);  \
  } while (0)

  STAGE(0, 0);
  for (int t = 0; t < nt; ++t) {
    const int cur = t & 1;
    __syncthreads();                       // drains prior stage (vmcnt 0)
    if (t + 1 < nt) STAGE(cur ^ 1, (t + 1) << 5);  // overlaps with compute
    const u16* bufp = smem + cur * 16384;
    bfrag ah[4], al4[4], bh4[4], bl4[4];
#pragma unroll
    for (int i = 0; i < 4; ++i) {
      const int rowA = wr * 64 + i * 16 + lr;
      const int rowB = wc * 64 + i * 16 + lr;
      ah[i]  = frag_at(bufp,          rowA, lg);
      al4[i] = frag_at(bufp + 4096,   rowA, lg);
      bh4[i] = frag_at(bufp + 8192,   rowB, lg);
      bl4[i] = frag_at(bufp + 12288,  rowB, lg);
    }
#pragma unroll
    for (int i = 0; i < 4; ++i)
#pragma unroll
      for (int j = 0; j < 4; ++j) {
        acc[i][j] = __builtin_amdgcn_mfma_f32_16x16x32_bf16(ah[i],  bh4[j], acc[i][j], 0, 0, 0);
        acc[i][j] = __builtin_amdgcn_mfma_f32_16x16x32_bf16(ah[i],  bl4[j], acc[i][j], 0, 0, 0);
        acc[i][j] = __builtin_amdgcn_mfma_f32_16x16x32_bf16(al4[i], bh4[j], acc[i][j], 0, 0, 0);
      }
  }
#undef STAGE

  // epilogue: C/D layout col = lane&15, row = (lane>>4)*4 + reg
  const float* mp_ = MASK ? (zh ? mask1 : mask0) : nullptr;
#pragma unroll
  for (int i = 0; i < 4; ++i)
#pragma unroll
    for (int j = 0; j < 4; ++j)
#pragma unroll
      for (int rr = 0; rr < 4; ++rr) {
        const int row = bm + wr * 64 + i * 16 + lg * 4 + rr;
        const int col = bn + wc * 64 + j * 16 + lr;
        float v = acc[i][j][rr];
        if (MASK) v *= mp_[(long)row * ldm + col];
        const long ci = coff + (long)row * ldc + col;
        if (OUTPAIR) {
          const u16 h = f2bf_rn(v);
          Ch[ci] = h;
          Cl[ci] = f2bf_rn(v - bf2f(h));
        } else if (ACCUM) {
          C[ci] += v;
        } else {
          C[ci] = v;
        }
      }
}

// ================= small kernels =================
__global__ void split_pair(const float* __restrict__ in, u16* __restrict__ oh,
                           u16* __restrict__ ol, long n) {
  for (long i = blockIdx.x * (long)blockDim.x + threadIdx.x; i < n;
       i += gridDim.x * (long)blockDim.x) {
    const float x = in[i];
    const u16 h = f2bf_rn(x);
    oh[i] = h;
    ol[i] = f2bf_rn(x - bf2f(h));
  }
}

// probs[:, h] (both b) split into a contiguous [b][S][S] pair
__global__ void split_pair_probs(const float* __restrict__ probs, int h,
                                 u16* __restrict__ oh, u16* __restrict__ ol) {
  const long n = (long)B << 20;  // B * S * S, S*S = 2^20
  for (long i = blockIdx.x * (long)blockDim.x + threadIdx.x; i < n;
       i += gridDim.x * (long)blockDim.x) {
    const long b = i >> 20;
    const long rr = i & ((1L << 20) - 1);
    const float x = probs[(b * H + h) * (1L << 20) + rr];
    const u16 hh = f2bf_rn(x);
    oh[i] = hh;
    ol[i] = f2bf_rn(x - bf2f(hh));
  }
}

// out pair [C][R] = transpose of in [R][C], optional per-input-row divisor
__global__ __launch_bounds__(256) void transpose_split(
    const float* __restrict__ in, const float* __restrict__ divv,
    u16* __restrict__ oh, u16* __restrict__ ol, int R, int C) {
  __shared__ float t[32][33];
  const int bx = blockIdx.x * 32;  // C dim
  const int by = blockIdx.y * 32;  // R dim
  const int x = threadIdx.x & 31, y = threadIdx.x >> 5;
#pragma unroll
  for (int j = 0; j < 4; ++j) {
    const int rr = by + y + j * 8;
    float v = in[(long)rr * C + bx + x];
    if (divv) v /= divv[rr];
    t[y + j * 8][x] = v;
  }
  __syncthreads();
#pragma unroll
  for (int j = 0; j < 4; ++j) {
    const int c = bx + y + j * 8;
    const float v = t[x][y + j * 8];
    const u16 h = f2bf_rn(v);
    oh[(long)c * R + by + x] = h;
    ol[(long)c * R + by + x] = f2bf_rn(v - bf2f(h));
  }
}

__global__ void cvec_partial(const float* __restrict__ W_OV,
                             const float* __restrict__ ub1,
                             const float* __restrict__ ub2,
                             float* __restrict__ ctmp) {
  const int o = blockIdx.x * 256 + threadIdx.x;
  const int h = blockIdx.y;
  const float* W = W_OV + (long)h * D * D;
  float acc = 0.f;
  for (int i = 0; i < D; ++i)
    acc = fmaf(W[(long)i * D + o], ub1[i] + ub2[i], acc);
  ctmp[h * D + o] = acc;
}

__global__ void cvec_reduce(const float* __restrict__ ctmp, float* __restrict__ cvec) {
  const int o = blockIdx.x * blockDim.x + threadIdx.x;
  if (o < D) {
    float a = 0.f;
    for (int h = 0; h < H; ++h) a += ctmp[h * D + o];
    cvec[o] = a;
  }
}

__global__ __launch_bounds__(64) void bias_vec(
    const float* __restrict__ enc_w, const float* __restrict__ b_O,
    const float* __restrict__ b_dec, const float* __restrict__ enc_b,
    const float* __restrict__ cvec, float* __restrict__ bias0,
    float* __restrict__ evec) {
  const int f = blockIdx.x;
  const int l = threadIdx.x;
  float s1 = 0.f, s2 = 0.f;
  for (int o = l; o < D; o += 64) {
    const float w = enc_w[(long)f * D + o];
    s1 = fmaf(w, b_O[o] - b_dec[o], s1);
    s2 = fmaf(w, cvec[o], s2);
  }
  for (int off = 32; off > 0; off >>= 1) {
    s1 += __shfl_down(s1, off);
    s2 += __shfl_down(s2, off);
  }
  if (l == 0) { bias0[f] = s1 + enc_b[f]; evec[f] = s2; }
}

__global__ __launch_bounds__(256) void transpose_dw(const float* __restrict__ in,
                                                    float* __restrict__ out) {
  __shared__ float t[32][33];
  const int bx = blockIdx.x * 32;
  const int by = blockIdx.y * 32;
  const int x = threadIdx.x & 31, y = threadIdx.x >> 5;
#pragma unroll
  for (int j = 0; j < 4; ++j) {
    const int row = y + j * 8;
    t[row][x] = in[(long)(by + row) * F + bx + x];
  }
  __syncthreads();
#pragma unroll
  for (int j = 0; j < 4; ++j) {
    const int row = y + j * 8;
    out[(long)(bx + row) * D + by + x] = t[x][row];
  }
}

// top-64 of (bias0 + evec/ln + featP) per row, IN PLACE: read row, zero it,
// relu+scatter top-64 back; record (v,idx) for recon.
__global__ __launch_bounds__(256) void topk_fused(
    float* __restrict__ featP, const float* __restrict__ bias0,
    const float* __restrict__ evec, const float* __restrict__ ln,
    float* __restrict__ topv, int* __restrict__ topi) {
  const int row = blockIdx.x;  // b*S+s
  const float rln = 1.f / ln[row];
  float* p0 = featP + (long)row * F;
  __shared__ float vals[F];
  __shared__ float rv[256];
  __shared__ int ri[256];
  for (int j = threadIdx.x; j < F; j += 256)
    vals[j] = bias0[j] + evec[j] * rln + p0[j];
  __syncthreads();
  for (int j = threadIdx.x; j < F; j += 256) p0[j] = 0.f;
  __syncthreads();
  for (int it = 0; it < TOPK; ++it) {
    float best = -3.4e38f;
    int bi = F;
    for (int j = threadIdx.x; j < F; j += 256) {
      const float v = vals[j];
      if (v > best) { best = v; bi = j; }  // strict > keeps lowest index
    }
    rv[threadIdx.x] = best; ri[threadIdx.x] = bi;
    __syncthreads();
    for (int s2 = 128; s2 > 0; s2 >>= 1) {
      if (threadIdx.x < s2) {
        const float ov = rv[threadIdx.x + s2];
        const int oi = ri[threadIdx.x + s2];
        if (ov > rv[threadIdx.x] ||
            (ov == rv[threadIdx.x] && oi < ri[threadIdx.x])) {
          rv[threadIdx.x] = ov; ri[threadIdx.x] = oi;
        }
      }
      __syncthreads();
    }
    if (threadIdx.x == 0) {
      const int idx = ri[0];
      const float v = fmaxf(rv[0], 0.f);
      p0[idx] = v;
      topv[row * TOPK + it] = v;
      topi[row * TOPK + it] = idx;
      vals[idx] = -3.4e38f;
    }
    __syncthreads();
  }
}

__global__ __launch_bounds__(256) void recon_kernel(
    const float* __restrict__ topv, const int* __restrict__ topi,
    const float* __restrict__ dec_wT, const float* __restrict__ b_dec,
    float* __restrict__ recon) {
  const int row = blockIdx.x;
  __shared__ float sv[TOPK];
  __shared__ int si[TOPK];
  if (threadIdx.x < TOPK) {
    sv[threadIdx.x] = topv[row * TOPK + threadIdx.x];
    si[threadIdx.x] = topi[row * TOPK + threadIdx.x];
  }
  __syncthreads();
  const int d0 = threadIdx.x, d1 = threadIdx.x + 256;
  float a0 = b_dec[d0], a1 = b_dec[d1];
  for (int j = 0; j < TOPK; ++j) {
    const float v = sv[j];
    const float* wp = dec_wT + (long)si[j] * D;
    a0 = fmaf(v, wp[d0], a0);
    a1 = fmaf(v, wp[d1], a1);
  }
  recon[(long)row * D + d0] = a0;
  recon[(long)row * D + d1] = a1;
}

// ================= launch =================
extern "C" void kernel_launch(void* const* d_in, const int* in_sizes, int n_in,
                              void* d_out, int out_size, void* d_ws, size_t ws_size,
                              hipStream_t stream) {
  const float* resid = (const float*)d_in[0];
  const float* ln    = (const float*)d_in[1];
  const float* probs = (const float*)d_in[2];
  const float* W_OV  = (const float*)d_in[3];
  const float* b_O   = (const float*)d_in[4];
  const float* enc_w = (const float*)d_in[5];
  const float* enc_b = (const float*)d_in[6];
  const float* b_dec = (const float*)d_in[7];
  const float* dec_w = (const float*)d_in[8];
  const float* up_dec_[2]  = {(const float*)d_in[9], (const float*)d_in[13]};
  const float* up_bdec_[2] = {(const float*)d_in[10], (const float*)d_in[14]};
  const float* pf_[2]      = {(const float*)d_in[11], (const float*)d_in[15]};
  const float* mask_[2]    = {(const float*)d_in[12], (const float*)d_in[16]};

  float* out_feat  = (float*)d_out;   // doubles as the dense P accumulator
  float* out_recon = out_feat + (size_t)B * S * F;
  float* P = out_feat;

  constexpr int NALL = D + 2 * F;  // 6656 = 52*128
  // ---- workspace layout: 189.8 MB (< 191.9 MB proven in round 2) ----
  float* ws = (float*)d_ws;
  size_t o = 0;
  float* bias0 = ws + o; o += F;
  float* evec  = ws + o; o += F;
  float* cvec  = ws + o; o += D;
  float* ctmp  = ws + o; o += (size_t)H * D;
  float* topv  = ws + o; o += (size_t)B * S * TOPK;
  int*   topi  = (int*)(ws + o); o += (size_t)B * S * TOPK;
  u16* encwPh = (u16*)(ws + o); o += (size_t)F * D / 2;
  u16* encwPl = (u16*)(ws + o); o += (size_t)F * D / 2;
  u16* wovPh  = (u16*)(ws + o); o += (size_t)H * D * D / 2;
  u16* wovPl  = (u16*)(ws + o); o += (size_t)H * D * D / 2;
  u16* udTh   = (u16*)(ws + o); o += (size_t)2 * F * D / 2;       // [u][F][D]
  u16* udTl   = (u16*)(ws + o); o += (size_t)2 * F * D / 2;
  u16* Gallh  = (u16*)(ws + o); o += (size_t)B * NALL * S / 2;    // [b][6656][S]
  u16* Galll  = (u16*)(ws + o); o += (size_t)B * NALL * S / 2;
  u16* Phh    = (u16*)(ws + o); o += (size_t)B * S * S / 2;       // per-h probs
  u16* Phl    = (u16*)(ws + o); o += (size_t)B * S * S / 2;
  u16* Ehh    = (u16*)(ws + o); o += (size_t)F * 512 / 2;         // per-h Eh
  u16* Ehl    = (u16*)(ws + o); o += (size_t)F * 512 / 2;
  const size_t xoff = o;                                          // dec_wT alias
  u16* Xallh  = (u16*)(ws + o); o += (size_t)B * S * NALL / 2;    // [b][q][6656]
  u16* Xalll  = (u16*)(ws + o); o += (size_t)B * S * NALL / 2;
  u16* vwh    = (u16*)(ws + o); o += (size_t)F * 3072 / 2;        // per-(h,u) vw
  u16* vwl    = (u16*)(ws + o); o += (size_t)F * 3072 / 2;
  float* dec_wT = ws + xoff;  // used only after h-loop (Xall dead by then)

  hipMemsetAsync(P, 0, sizeof(float) * (size_t)B * S * F, stream);

  // ---- operand prep ----
  split_pair<<<1024, 256, 0, stream>>>(enc_w, encwPh, encwPl, (long)F * D);
  split_pair<<<1024, 256, 0, stream>>>(W_OV, wovPh, wovPl, (long)H * D * D);
  for (int b = 0; b < B; ++b) {
    // Gall rows 0..511 = resid^T/ln
    transpose_split<<<dim3(D / 32, S / 32), 256, 0, stream>>>(
        resid + (size_t)b * S * D, ln + (size_t)b * S,
        Gallh + ((size_t)b * NALL + 0) * S, Galll + ((size_t)b * NALL + 0) * S,
        S, D);
    // Gall rows 512+u*3072 .. = pf_u^T/ln
    for (int u = 0; u < 2; ++u)
      transpose_split<<<dim3(F / 32, S / 32), 256, 0, stream>>>(
          pf_[u] + (size_t)b * S * F, ln + (size_t)b * S,
          Gallh + ((size_t)b * NALL + 512 + (size_t)u * F) * S,
          Galll + ((size_t)b * NALL + 512 + (size_t)u * F) * S, S, F);
  }
  for (int u = 0; u < 2; ++u)
    transpose_split<<<dim3(F / 32, D / 32), 256, 0, stream>>>(
        up_dec_[u], nullptr, udTh + (size_t)u * F * D, udTl + (size_t)u * F * D,
        D, F);
  cvec_partial<<<dim3(2, 8), 256, 0, stream>>>(W_OV, up_bdec_[0], up_bdec_[1], ctmp);
  cvec_reduce<<<2, 256, 0, stream>>>(ctmp, cvec);
  bias_vec<<<F, 64, 0, stream>>>(enc_w, b_O, b_dec, enc_b, cvec, bias0, evec);

  // ---- per-head pipeline ----
  for (int h = 0; h < H; ++h) {
    // probs[:,h] split pair (both b, one dispatch)
    split_pair_probs<<<2048, 256, 0, stream>>>(probs, h, Phh, Phl);
    // Eh[f,i] = sum_o enc_w[f,o] * W_OV[h,i,o] -> pair [F][512]
    gemm_split3<false, false, false, true><<<96, 256, 0, stream>>>(
        encwPh, encwPl, wovPh + (size_t)h * D * D, wovPl + (size_t)h * D * D,
        nullptr, Ehh, Ehl, nullptr, nullptr, 0,
        512, 512, 512, 512, 4, 24, 1, 0L, 0L, 0L, 0L, 0L, 0L);
    // Xall[b][q][0:6656] = probs_h[b] @ Gall[b]^T (causal) -> pair, ldc=6656
    gemm_split3<false, true, false, true><<<832, 256, 0, stream>>>(
        Phh, Phl, Gallh, Galll, nullptr, Xallh, Xalll, nullptr, nullptr, 0,
        S, S, S, NALL, NALL / 128, 8, 2,
        (long)S * S, 0L, (long)NALL * S, 0L, (long)S * NALL, 0L);
    // P[b] += Xall[:, 0:512] @ Eh^T  (K=512)
    gemm_split3<true, false, false, false><<<384, 256, 0, stream>>>(
        Xallh, Xalll, Ehh, Ehl, P, nullptr, nullptr, nullptr, nullptr, 0,
        512, NALL, 512, F, 24, 8, 2,
        (long)S * NALL, 0L, 0L, 0L, (long)S * F, 0L);

    for (int u = 0; u < 2; ++u) {
      // vw[d][n] = (Eh @ udT_u^T)[d][n] * mask_u[d][n] -> pair [F][3072]
      gemm_split3<false, false, true, true><<<576, 256, 0, stream>>>(
          Ehh, Ehl, udTh + (size_t)u * F * D, udTl + (size_t)u * F * D,
          nullptr, vwh, vwl, mask_[u], nullptr, F,
          512, 512, 512, 3072, 24, 24, 1, 0L, 0L, 0L, 0L, 0L, 0L);
      // P[b] += Xall[:, 512+u*3072 : +3072] @ vw^T  (K=3072)
      gemm_split3<true, false, false, false><<<384, 256, 0, stream>>>(
          Xallh + 512 + (size_t)u * F, Xalll + 512 + (size_t)u * F,
          vwh, vwl, P, nullptr, nullptr, nullptr, nullptr, 0,
          3072, NALL, 3072, F, 24, 8, 2,
          (long)S * NALL, 0L, 0L, 0L, (long)S * F, 0L);
    }
  }

  // ---- tail: dec_w transpose (into dead Xall region), topk in-place, recon ----
  transpose_dw<<<dim3(F / 32, D / 32), 256, 0, stream>>>(dec_w, dec_wT);
  topk_fused<<<B * S, 256, 0, stream>>>(P, bias0, evec, ln, topv, topi);
  recon_kernel<<<B * S, 256, 0, stream>>>(topv, topi, dec_wT, b_dec, out_recon);
}